// Round 1
// baseline (101.839 us; speedup 1.0000x reference)
//
#include <hip/hip_runtime.h>
#include <math.h>

#define B   8
#define NL  256
#define NP  16384
#define DL  10
#define DP  4

// constants from the reference
#define DELTA  0.01f
// EPS = A_C = B_C = 1.0, L_BIND = 1.0, L_MREG = 0.1

// ---- fast 1-ulp HW transcendentals (guarded fallbacks) ----
static __device__ __forceinline__ float fast_sqrtf(float x) {
#if __has_builtin(__builtin_amdgcn_sqrtf)
    return __builtin_amdgcn_sqrtf(x);   // v_sqrt_f32, ~1 ulp
#else
    return sqrtf(x);
#endif
}
static __device__ __forceinline__ float fast_rcpf(float x) {
#if __has_builtin(__builtin_amdgcn_rcpf)
    return __builtin_amdgcn_rcpf(x);    // v_rcp_f32, ~1 ulp
#else
    return 1.0f / x;
#endif
}

// ---------------------------------------------------------------------------
// Kernel 1: prep — charge lookup via first-max argmax, pack SoA float4
//   blocks [0,512)   : protein atoms (B*NP = 131072), one per thread
//   blocks [512,520) : ligand atoms  (B*NL = 2048),   one per thread
// ---------------------------------------------------------------------------
__global__ __launch_bounds__(256) void prep_kernel(
    const float* __restrict__ prot_coords,   // (B,NP,3)
    const float* __restrict__ prot_feat,     // (B,NP,DP)
    const float* __restrict__ tc2,           // (B,NL,3)
    const float* __restrict__ lig_feat,      // (B,NL,DL)
    const float* __restrict__ lig_tab,       // (DL)
    const float* __restrict__ prot_tab,      // (DP)
    float4* __restrict__ pro4,               // out: (B*NP) {x,y,z,q}
    float4* __restrict__ lig4)               // out: (B*NL) {x,y,z,q}
{
    if (blockIdx.x < 512) {
        int i = blockIdx.x * 256 + threadIdx.x;           // [0, B*NP)
        const float* f = prot_feat + (size_t)i * DP;
        float best = f[0]; int bi = 0;
        #pragma unroll
        for (int j = 1; j < DP; ++j) { float v = f[j]; if (v > best) { best = v; bi = j; } }
        const float* c = prot_coords + (size_t)i * 3;
        pro4[i] = make_float4(c[0], c[1], c[2], prot_tab[bi]);
    } else {
        int i = (blockIdx.x - 512) * 256 + threadIdx.x;   // [0, B*NL)
        if (i < B * NL) {
            const float* f = lig_feat + (size_t)i * DL;
            float best = f[0]; int bi = 0;
            #pragma unroll
            for (int j = 1; j < DL; ++j) { float v = f[j]; if (v > best) { best = v; bi = j; } }
            const float* c = tc2 + (size_t)i * 3;
            lig4[i] = make_float4(c[0], c[1], c[2], lig_tab[bi]);
        }
    }
}

// ---------------------------------------------------------------------------
// Kernel 2: pair — binding energy partial sums.
//   grid = 2048 blocks x 256 threads.
//   block id -> b (8) x pchunk (64) x lchunk (4)
//   thread: protein atom m = pchunk*256 + tid (registers), loops 64 ligand
//   atoms (wave-uniform index -> scalar s_load_dwordx4).
//   d2 via DIRECT DIFFERENCE (accurate; see numerics note in journal).
// ---------------------------------------------------------------------------
__global__ __launch_bounds__(256) void pair_kernel(
    const float4* __restrict__ pro4,
    const float4* __restrict__ lig4,
    double* __restrict__ partials)           // (2048 * 2): {elec, vdw}
{
    const int blk    = blockIdx.x;
    const int lchunk = blk & 3;
    const int pchunk = (blk >> 2) & 63;
    const int b      = blk >> 8;

    const int m = pchunk * 256 + threadIdx.x;
    const float4 p = pro4[b * NP + m];

    const int lbase = b * NL + lchunk * 64;

    float elec = 0.0f, vdw = 0.0f;
    #pragma unroll 4
    for (int j = 0; j < 64; ++j) {
        const float4 l = lig4[lbase + j];    // uniform index -> s_load
        float dx = l.x - p.x;
        float dy = l.y - p.y;
        float dz = l.z - p.z;
        float d2 = fmaf(dx, dx, fmaf(dy, dy, dz * dz));
        float d  = fast_sqrtf(d2) + DELTA;   // ref: sqrt(max(d2,0)) + DELTA
        float inv  = fast_rcpf(d);
        float inv2 = inv * inv;
        float inv4 = inv2 * inv2;
        float inv6 = inv4 * inv2;
        elec = fmaf(l.w * p.w, inv, elec);           // /EPS with EPS=1
        vdw  = fmaf(inv6, inv6 - 1.0f, vdw);         // inv12 - inv6 (A=B=1)
    }

    // block reduction in fp64 (deterministic, no atomics)
    double e = (double)elec, v = (double)vdw;
    #pragma unroll
    for (int off = 32; off > 0; off >>= 1) {
        e += __shfl_down(e, off, 64);
        v += __shfl_down(v, off, 64);
    }
    __shared__ double se[4], sv[4];
    const int lane = threadIdx.x & 63;
    const int w    = threadIdx.x >> 6;
    if (lane == 0) { se[w] = e; sv[w] = v; }
    __syncthreads();
    if (threadIdx.x == 0) {
        partials[2 * blk]     = se[0] + se[1] + se[2] + se[3];
        partials[2 * blk + 1] = sv[0] + sv[1] + sv[2] + sv[3];
    }
}

// ---------------------------------------------------------------------------
// Kernel 3: finalize — reduce partials + masked MSE / mreg terms, write scalar.
//   1 block x 256 threads.
// ---------------------------------------------------------------------------
__global__ __launch_bounds__(256) void finalize_kernel(
    const float*  __restrict__ pred_noise,   // (B,NL,3)
    const float*  __restrict__ tgt_coords,   // (B,NL,3)
    const float*  __restrict__ scaf_coords,  // (B,NL,3)
    const float*  __restrict__ mask,         // (B,NL)
    const double* __restrict__ partials,     // (2048*2)
    float* __restrict__ out)
{
    double de = 0.0, mr = 0.0, ms = 0.0, el = 0.0, vd = 0.0;

    for (int i = threadIdx.x; i < B * NL; i += 256) {
        float mk = mask[i];
        float a0 = pred_noise[3*i+0] - tgt_coords[3*i+0];
        float a1 = pred_noise[3*i+1] - tgt_coords[3*i+1];
        float a2 = pred_noise[3*i+2] - tgt_coords[3*i+2];
        de += (double)mk * ((double)a0*a0 + (double)a1*a1 + (double)a2*a2);
        float s0 = scaf_coords[3*i+0] - tgt_coords[3*i+0];
        float s1 = scaf_coords[3*i+1] - tgt_coords[3*i+1];
        float s2 = scaf_coords[3*i+2] - tgt_coords[3*i+2];
        mr += (double)mk * ((double)s0*s0 + (double)s1*s1 + (double)s2*s2);
        ms += (double)mk;
    }
    for (int i = threadIdx.x; i < 2048; i += 256) {
        el += partials[2*i];
        vd += partials[2*i + 1];
    }

    // reduce 5 doubles across the block
    #pragma unroll
    for (int off = 32; off > 0; off >>= 1) {
        de += __shfl_down(de, off, 64);
        mr += __shfl_down(mr, off, 64);
        ms += __shfl_down(ms, off, 64);
        el += __shfl_down(el, off, 64);
        vd += __shfl_down(vd, off, 64);
    }
    __shared__ double s[4][5];
    const int lane = threadIdx.x & 63;
    const int w    = threadIdx.x >> 6;
    if (lane == 0) { s[w][0]=de; s[w][1]=mr; s[w][2]=ms; s[w][3]=el; s[w][4]=vd; }
    __syncthreads();
    if (threadIdx.x == 0) {
        de = s[0][0]+s[1][0]+s[2][0]+s[3][0];
        mr = s[0][1]+s[1][1]+s[2][1]+s[3][1];
        ms = s[0][2]+s[1][2]+s[2][2]+s[3][2];
        el = s[0][3]+s[1][3]+s[2][3]+s[3][3];
        vd = s[0][4]+s[1][4]+s[2][4]+s[3][4];
        double loss_bind = (el + vd) / (double)B;   // mean over batch
        double loss = de / ms + 1.0 * loss_bind + 0.1 * (mr / ms);
        out[0] = (float)loss;
    }
}

// ---------------------------------------------------------------------------
extern "C" void kernel_launch(void* const* d_in, const int* in_sizes, int n_in,
                              void* d_out, int out_size, void* d_ws, size_t ws_size,
                              hipStream_t stream)
{
    const float* pred_noise  = (const float*)d_in[0];
    const float* tgt_coords  = (const float*)d_in[1];
    const float* scaf_coords = (const float*)d_in[2];
    const float* tc2         = (const float*)d_in[3];
    const float* lig_feat    = (const float*)d_in[4];
    const float* mask        = (const float*)d_in[5];
    const float* prot_coords = (const float*)d_in[6];
    const float* prot_feat   = (const float*)d_in[7];
    const float* lig_tab     = (const float*)d_in[8];
    const float* prot_tab    = (const float*)d_in[9];
    float* out = (float*)d_out;

    // ws layout (all 16B-aligned):
    //   pro4     : B*NP  float4  = 2 MiB
    //   lig4     : B*NL  float4  = 32 KiB
    //   partials : 2048*2 double = 32 KiB
    char* ws = (char*)d_ws;
    float4* pro4     = (float4*)ws;
    float4* lig4     = (float4*)(ws + (size_t)B * NP * sizeof(float4));
    double* partials = (double*)(ws + (size_t)B * NP * sizeof(float4)
                                    + (size_t)B * NL * sizeof(float4));

    prep_kernel<<<520, 256, 0, stream>>>(prot_coords, prot_feat, tc2, lig_feat,
                                         lig_tab, prot_tab, pro4, lig4);
    pair_kernel<<<2048, 256, 0, stream>>>(pro4, lig4, partials);
    finalize_kernel<<<1, 256, 0, stream>>>(pred_noise, tgt_coords, scaf_coords,
                                           mask, partials, out);
}

// Round 2
// 94.969 us; speedup vs baseline: 1.0723x; 1.0723x over previous
//
#include <hip/hip_runtime.h>
#include <math.h>

#define B   8
#define NL  256
#define NP  16384
#define DL  10
#define DP  4

#define DELTA  0.01f
// EPS = A_C = B_C = 1.0, L_BIND = 1.0, L_MREG = 0.1

// ---- 1-ulp HW transcendentals (guarded fallbacks) ----
static __device__ __forceinline__ float fast_sqrtf(float x) {
#if __has_builtin(__builtin_amdgcn_sqrtf)
    return __builtin_amdgcn_sqrtf(x);   // v_sqrt_f32
#else
    return sqrtf(x);
#endif
}
static __device__ __forceinline__ float fast_rcpf(float x) {
#if __has_builtin(__builtin_amdgcn_rcpf)
    return __builtin_amdgcn_rcpf(x);    // v_rcp_f32
#else
    return 1.0f / x;
#endif
}

// ws layout: partials[0 .. 2*2048)   : {elec, vdw} per binding block (fp64)
//            partials[4096 .. 4096+24): {de, mr, ms} per mse block (8 blocks)
#define NBIND 2048
#define NMSE  8

// ---------------------------------------------------------------------------
// Kernel 1: fused pair + mse partials.
//   blocks [0,2048)      : binding energy. blk -> b(8) x pchunk(64) x lchunk(4)
//     - stage 64 ligand atoms (coords + argmax charge) into LDS
//     - thread owns protein atom pchunk*256+tid (coords + inline argmax charge)
//     - 64-iter inner loop, LDS broadcast reads
//   blocks [2048,2056)   : masked MSE / mreg / mask-sum partials
//   Per-block fp64 deterministic reduction -> partials (no atomics).
// ---------------------------------------------------------------------------
__global__ __launch_bounds__(256) void pair_mse_kernel(
    const float* __restrict__ prot_coords,   // (B,NP,3)
    const float* __restrict__ prot_feat,     // (B,NP,DP)
    const float* __restrict__ tc2,           // (B,NL,3)
    const float* __restrict__ lig_feat,      // (B,NL,DL)
    const float* __restrict__ lig_tab,       // (DL)
    const float* __restrict__ prot_tab,      // (DP)
    const float* __restrict__ pred_noise,    // (B,NL,3)
    const float* __restrict__ tgt_coords,    // (B,NL,3)
    const float* __restrict__ scaf_coords,   // (B,NL,3)
    const float* __restrict__ mask,          // (B,NL)
    double* __restrict__ partials)
{
    const int tid = threadIdx.x;
    const int blk = blockIdx.x;

    if (blk < NBIND) {
        // ---------------- binding energy ----------------
        const int lchunk = blk & 3;
        const int pchunk = (blk >> 2) & 63;
        const int b      = blk >> 8;

        __shared__ float4 slig[64];
        if (tid < 64) {
            const int li = b * NL + lchunk * 64 + tid;
            const float* f = lig_feat + (size_t)li * DL;
            float best = f[0]; float q = lig_tab[0];
            #pragma unroll
            for (int j = 1; j < DL; ++j) {
                float v = f[j];
                float t = lig_tab[j];            // uniform -> s_load
                if (v > best) { best = v; q = t; }
            }
            const float* c = tc2 + (size_t)li * 3;
            slig[tid] = make_float4(c[0], c[1], c[2], q);
        }

        // protein atom for this thread (while staging happens)
        const int m = b * NP + pchunk * 256 + tid;
        const float* pc = prot_coords + (size_t)m * 3;
        const float px = pc[0], py = pc[1], pz = pc[2];
        const float4 pf = reinterpret_cast<const float4*>(prot_feat)[m];
        float qb = pf.x, qp = prot_tab[0];
        { float t = prot_tab[1]; if (pf.y > qb) { qb = pf.y; qp = t; } }
        { float t = prot_tab[2]; if (pf.z > qb) { qb = pf.z; qp = t; } }
        { float t = prot_tab[3]; if (pf.w > qb) { qb = pf.w; qp = t; } }

        __syncthreads();

        float eacc = 0.0f, vacc = 0.0f;
        #pragma unroll 8
        for (int j = 0; j < 64; ++j) {
            const float4 l = slig[j];            // ds_read_b128 broadcast
            float dx = l.x - px;
            float dy = l.y - py;
            float dz = l.z - pz;
            float d2 = fmaf(dx, dx, fmaf(dy, dy, dz * dz));
            float d  = fast_sqrtf(d2) + DELTA;
            float inv  = fast_rcpf(d);
            float inv2 = inv * inv;
            float inv6 = inv2 * inv2 * inv2;
            eacc = fmaf(l.w, inv, eacc);                 // ql * inv (qp applied after)
            vacc = fmaf(inv6, inv6 - 1.0f, vacc);        // inv12 - inv6
        }
        double e = (double)(qp * eacc);
        double v = (double)vacc;

        #pragma unroll
        for (int off = 32; off > 0; off >>= 1) {
            e += __shfl_down(e, off, 64);
            v += __shfl_down(v, off, 64);
        }
        __shared__ double se[4], sv[4];
        const int lane = tid & 63, w = tid >> 6;
        if (lane == 0) { se[w] = e; sv[w] = v; }
        __syncthreads();
        if (tid == 0) {
            partials[2 * blk]     = se[0] + se[1] + se[2] + se[3];
            partials[2 * blk + 1] = sv[0] + sv[1] + sv[2] + sv[3];
        }
    } else {
        // ---------------- masked MSE / mreg partials ----------------
        const int idx = blk - NBIND;             // [0,8)
        const int i   = idx * 256 + tid;         // [0, B*NL)
        float mk = mask[i];
        float a0 = pred_noise[3*i+0] - tgt_coords[3*i+0];
        float a1 = pred_noise[3*i+1] - tgt_coords[3*i+1];
        float a2 = pred_noise[3*i+2] - tgt_coords[3*i+2];
        double de = (double)mk * ((double)a0*a0 + (double)a1*a1 + (double)a2*a2);
        float s0 = scaf_coords[3*i+0] - tgt_coords[3*i+0];
        float s1 = scaf_coords[3*i+1] - tgt_coords[3*i+1];
        float s2 = scaf_coords[3*i+2] - tgt_coords[3*i+2];
        double mr = (double)mk * ((double)s0*s0 + (double)s1*s1 + (double)s2*s2);
        double ms = (double)mk;

        #pragma unroll
        for (int off = 32; off > 0; off >>= 1) {
            de += __shfl_down(de, off, 64);
            mr += __shfl_down(mr, off, 64);
            ms += __shfl_down(ms, off, 64);
        }
        __shared__ double s[4][3];
        const int lane = tid & 63, w = tid >> 6;
        if (lane == 0) { s[w][0] = de; s[w][1] = mr; s[w][2] = ms; }
        __syncthreads();
        if (tid == 0) {
            partials[2*NBIND + idx*3 + 0] = s[0][0]+s[1][0]+s[2][0]+s[3][0];
            partials[2*NBIND + idx*3 + 1] = s[0][1]+s[1][1]+s[2][1]+s[3][1];
            partials[2*NBIND + idx*3 + 2] = s[0][2]+s[1][2]+s[2][2]+s[3][2];
        }
    }
}

// ---------------------------------------------------------------------------
// Kernel 2: finalize — reduce all partials, write scalar loss.
// ---------------------------------------------------------------------------
__global__ __launch_bounds__(256) void finalize_kernel(
    const double* __restrict__ partials,
    float* __restrict__ out)
{
    const int tid = threadIdx.x;
    double el = 0.0, vd = 0.0;
    for (int i = tid; i < NBIND; i += 256) {
        el += partials[2*i];
        vd += partials[2*i + 1];
    }
    double de = 0.0, mr = 0.0, ms = 0.0;
    if (tid < NMSE) {
        de = partials[2*NBIND + tid*3 + 0];
        mr = partials[2*NBIND + tid*3 + 1];
        ms = partials[2*NBIND + tid*3 + 2];
    }
    #pragma unroll
    for (int off = 32; off > 0; off >>= 1) {
        el += __shfl_down(el, off, 64);
        vd += __shfl_down(vd, off, 64);
        de += __shfl_down(de, off, 64);
        mr += __shfl_down(mr, off, 64);
        ms += __shfl_down(ms, off, 64);
    }
    __shared__ double s[4][5];
    const int lane = tid & 63, w = tid >> 6;
    if (lane == 0) { s[w][0]=el; s[w][1]=vd; s[w][2]=de; s[w][3]=mr; s[w][4]=ms; }
    __syncthreads();
    if (tid == 0) {
        el = s[0][0]+s[1][0]+s[2][0]+s[3][0];
        vd = s[0][1]+s[1][1]+s[2][1]+s[3][1];
        de = s[0][2]+s[1][2]+s[2][2]+s[3][2];
        mr = s[0][3]+s[1][3]+s[2][3]+s[3][3];
        ms = s[0][4]+s[1][4]+s[2][4]+s[3][4];
        double loss_bind = (el + vd) / (double)B;
        double loss = de / ms + loss_bind + 0.1 * (mr / ms);
        out[0] = (float)loss;
    }
}

// ---------------------------------------------------------------------------
extern "C" void kernel_launch(void* const* d_in, const int* in_sizes, int n_in,
                              void* d_out, int out_size, void* d_ws, size_t ws_size,
                              hipStream_t stream)
{
    const float* pred_noise  = (const float*)d_in[0];
    const float* tgt_coords  = (const float*)d_in[1];
    const float* scaf_coords = (const float*)d_in[2];
    const float* tc2         = (const float*)d_in[3];
    const float* lig_feat    = (const float*)d_in[4];
    const float* mask        = (const float*)d_in[5];
    const float* prot_coords = (const float*)d_in[6];
    const float* prot_feat   = (const float*)d_in[7];
    const float* lig_tab     = (const float*)d_in[8];
    const float* prot_tab    = (const float*)d_in[9];
    float* out = (float*)d_out;

    double* partials = (double*)d_ws;   // (2*2048 + 24) doubles = 33 KB

    pair_mse_kernel<<<NBIND + NMSE, 256, 0, stream>>>(
        prot_coords, prot_feat, tc2, lig_feat, lig_tab, prot_tab,
        pred_noise, tgt_coords, scaf_coords, mask, partials);
    finalize_kernel<<<1, 256, 0, stream>>>(partials, out);
}